// Round 18
// baseline (181.879 us; speedup 1.0000x reference)
//
#include <hip/hip_runtime.h>
#include <hip/hip_bf16.h>
#include <type_traits>

// ---------------- types & helpers ----------------
typedef unsigned short u16;
typedef __attribute__((ext_vector_type(8))) short bf16x8;   // 8 bf16 in 4 VGPRs
typedef __attribute__((ext_vector_type(4))) float f32x4;

#define AS1 __attribute__((address_space(1)))
#define AS3 __attribute__((address_space(3)))

__device__ __forceinline__ u16 f2bf(float x) {
  unsigned u = __float_as_uint(x);
  u += 0x7fffu + ((u >> 16) & 1u);   // round-to-nearest-even
  return (u16)(u >> 16);
}

// B=4, T=2048, C=1024, H=16, D=64
#define TT 2048
#define CC 1024
#define HH 16
#define DD 64

// scale * log2(e), folded into Q at the QKV epilogue
#define SL2E 0.1803368801111137f

// ---------------- fp32 -> bf16 convert (x), vectorized 8/thread ----------------
__global__ __launch_bounds__(256) void conv_f2bf(const float* __restrict__ in,
                                                 u16* __restrict__ out) {
  int i = blockIdx.x * 256 + threadIdx.x;
  const float4* p = (const float4*)in;
  float4 f0 = p[i * 2];
  float4 f1 = p[i * 2 + 1];
  u16 vv[8] = {f2bf(f0.x), f2bf(f0.y), f2bf(f0.z), f2bf(f0.w),
               f2bf(f1.x), f2bf(f1.y), f2bf(f1.z), f2bf(f1.w)};
  ((uint4*)out)[i] = *(const uint4*)vv;
}

// ---------------- weight transpose+convert: wt[n][k] = bf(w[k][n]) ----------------
__global__ __launch_bounds__(256) void transw(const float* __restrict__ w0,
                                              const float* __restrict__ w1,
                                              const float* __restrict__ w2,
                                              const float* __restrict__ w3,
                                              u16* __restrict__ wt_all) {
  __shared__ __align__(16) u16 tile[32][33];
  const float* w = blockIdx.z == 0 ? w0 : blockIdx.z == 1 ? w1 : blockIdx.z == 2 ? w2 : w3;
  u16* wt = wt_all + (size_t)blockIdx.z * (CC * CC);
  int k0 = blockIdx.y * 32, n0 = blockIdx.x * 32;
  int tx = threadIdx.x, ty = threadIdx.y;
#pragma unroll
  for (int i = 0; i < 4; ++i) {
    int r = ty + i * 8;
    tile[r][tx] = f2bf(w[(size_t)(k0 + r) * CC + n0 + tx]);
  }
  __syncthreads();
#pragma unroll
  for (int i = 0; i < 4; ++i) {
    int r = ty + i * 8;
    wt[(size_t)(n0 + r) * CC + k0 + tx] = tile[tx][r];
  }
}

// ---------------- GEMM bodies, BK=64 (32 MFMA per barrier pair) ----------------
// LDS rows are 128B -> XOR-swizzled on 16B slots: phys = logical ^ (row&7),
// applied on BOTH the gload_lds SOURCE column and the fragment reads (G21).

// QKV GEMM: A = xb bf16, B = wt bf16 -> [B,H,T,D]; Q pre-scaled by SL2E.
__global__ __launch_bounds__(256) void gemm_qkv(const u16* __restrict__ Xb,
                                                const u16* __restrict__ wt_all,
                                                const float* __restrict__ bq,
                                                const float* __restrict__ bk,
                                                const float* __restrict__ bv,
                                                u16* __restrict__ Qb,
                                                u16* __restrict__ Kb,
                                                u16* __restrict__ Vb) {
  __shared__ __align__(16) u16 As[128 * 64];
  __shared__ __align__(16) u16 Bs[128 * 64];
  const int z = blockIdx.z;
  const u16* Bt = wt_all + (size_t)z * (CC * CC);
  const float* bias = z == 0 ? bq : z == 1 ? bk : bv;
  u16* dst = z == 0 ? Qb : z == 1 ? Kb : Vb;
  const float oscale = (z == 0) ? SL2E : 1.0f;

  const int tid = threadIdx.x;
  const int l = tid & 63, w = tid >> 6;
  const int m0 = blockIdx.y * 128, n0 = blockIdx.x * 128;
  const int mw = (w >> 1) * 64, nw = (w & 1) * 64;

  auto stage = [&](int kt) {
    int kk = kt * 64;
#pragma unroll
    for (int it = 0; it < 4; ++it) {
      int c = tid + it * 256;                 // 1024 chunks of 16B per tile
      int row = c >> 3, s = c & 7;
      int g = s ^ (row & 7);                  // inverse-swizzled source column
      __builtin_amdgcn_global_load_lds(
          (const AS1 void*)(Bt + (size_t)(n0 + row) * CC + kk + g * 8),
          (AS3 void*)(Bs + c * 8), 16, 0, 0);
      __builtin_amdgcn_global_load_lds(
          (const AS1 void*)(Xb + (size_t)(m0 + row) * CC + kk + g * 8),
          (AS3 void*)(As + c * 8), 16, 0, 0);
    }
  };

  f32x4 acc[4][4] = {};
  stage(0);
  const int KT = CC >> 6;                     // 16 K-steps
  for (int kt = 0; kt < KT; ++kt) {
    __syncthreads();
#pragma unroll
    for (int half = 0; half < 2; ++half) {
      bf16x8 a[4], b[4];
#pragma unroll
      for (int i = 0; i < 4; ++i) {
        int ra = mw + i * 16 + (l & 15);
        int sa = (half * 4 + (l >> 4)) ^ (ra & 7);
        a[i] = *(const bf16x8*)(As + ra * 64 + sa * 8);
        int rb = nw + i * 16 + (l & 15);
        int sb = (half * 4 + (l >> 4)) ^ (rb & 7);
        b[i] = *(const bf16x8*)(Bs + rb * 64 + sb * 8);
      }
#pragma unroll
      for (int i = 0; i < 4; ++i)
#pragma unroll
        for (int j = 0; j < 4; ++j)
          acc[i][j] = __builtin_amdgcn_mfma_f32_16x16x32_bf16(a[i], b[j], acc[i][j], 0, 0, 0);
    }
    __syncthreads();
    if (kt + 1 < KT) stage(kt + 1);
  }

#pragma unroll
  for (int i = 0; i < 4; ++i) {
    int rowb = m0 + mw + i * 16 + ((l >> 4) << 2);
#pragma unroll
    for (int j = 0; j < 4; ++j) {
      int col = n0 + nw + j * 16 + (l & 15);
      float bv_ = bias[col];
      int h = col >> 6, d = col & 63;
#pragma unroll
      for (int r = 0; r < 4; ++r) {
        int row = rowb + r;
        int bb = row >> 11, t = row & (TT - 1);
        dst[(((size_t)(bb * HH + h)) * TT + t) * DD + d] = f2bf((acc[i][j][r] + bv_) * oscale);
      }
    }
  }
}

// OUT GEMM: A = O in [B,H,T,D] bf16 (gathered), B = wo^T; fp32 out.
__global__ __launch_bounds__(256) void gemm_out(const u16* __restrict__ Oh,
                                                const u16* __restrict__ Bt,
                                                const float* __restrict__ bias,
                                                float* __restrict__ dst) {
  __shared__ __align__(16) u16 As[128 * 64];
  __shared__ __align__(16) u16 Bs[128 * 64];
  const int tid = threadIdx.x;
  const int l = tid & 63, w = tid >> 6;
  const int m0 = blockIdx.y * 128, n0 = blockIdx.x * 128;
  const int mw = (w >> 1) * 64, nw = (w & 1) * 64;

  auto stage = [&](int kt) {
    int kk = kt * 64;
#pragma unroll
    for (int it = 0; it < 4; ++it) {
      int c = tid + it * 256;
      int row = c >> 3, s = c & 7;
      int g = s ^ (row & 7);
      __builtin_amdgcn_global_load_lds(
          (const AS1 void*)(Bt + (size_t)(n0 + row) * CC + kk + g * 8),
          (AS3 void*)(Bs + c * 8), 16, 0, 0);
      // A gather from [B,H,T,D]: k = h*64+d; 8-chunks never cross head boundary
      int gr = m0 + row, gk = kk + g * 8;
      int bb = gr >> 11, t = gr & (TT - 1);
      int h = gk >> 6, d = gk & 63;
      __builtin_amdgcn_global_load_lds(
          (const AS1 void*)(Oh + (((size_t)(bb * HH + h)) * TT + t) * DD + d),
          (AS3 void*)(As + c * 8), 16, 0, 0);
    }
  };

  f32x4 acc[4][4] = {};
  stage(0);
  const int KT = CC >> 6;
  for (int kt = 0; kt < KT; ++kt) {
    __syncthreads();
#pragma unroll
    for (int half = 0; half < 2; ++half) {
      bf16x8 a[4], b[4];
#pragma unroll
      for (int i = 0; i < 4; ++i) {
        int ra = mw + i * 16 + (l & 15);
        int sa = (half * 4 + (l >> 4)) ^ (ra & 7);
        a[i] = *(const bf16x8*)(As + ra * 64 + sa * 8);
        int rb = nw + i * 16 + (l & 15);
        int sb = (half * 4 + (l >> 4)) ^ (rb & 7);
        b[i] = *(const bf16x8*)(Bs + rb * 64 + sb * 8);
      }
#pragma unroll
      for (int i = 0; i < 4; ++i)
#pragma unroll
        for (int j = 0; j < 4; ++j)
          acc[i][j] = __builtin_amdgcn_mfma_f32_16x16x32_bf16(a[i], b[j], acc[i][j], 0, 0, 0);
    }
    __syncthreads();
    if (kt + 1 < KT) stage(kt + 1);
  }

#pragma unroll
  for (int i = 0; i < 4; ++i) {
    int rowb = m0 + mw + i * 16 + ((l >> 4) << 2);
#pragma unroll
    for (int j = 0; j < 4; ++j) {
      int col = n0 + nw + j * 16 + (l & 15);
      float bv_ = bias[col];
#pragma unroll
      for (int r = 0; r < 4; ++r)
        dst[(size_t)(rowb + r) * CC + col] = acc[i][j][r] + bv_;
    }
  }
}

// ---------------- causal flash attention v11 ----------------
// v9 (round-15/17 best) + CU-load-balanced qt permutation: with 4 blocks/CU
// exactly resident and linear round-robin dispatch, CU c gets blockIdx.y in
// {j, j+4, j+8, j+12}; perm p=[0..3,15..12,7..4,8..11] makes every quartet's
// chunk total equal (68) -> removes the ~15% per-CU work-imbalance tail.
__global__ __launch_bounds__(512, 4) void attn_kernel(u16* __restrict__ Q,
                                                      const u16* __restrict__ K,
                                                      const u16* __restrict__ V) {
  __shared__ __align__(16) u16 Ks[2][64 * 64];   // [key][d], swizzled
  __shared__ __align__(16) u16 Vt[2][64 * 64];   // [d][key], swizzled
  __shared__ __align__(16) u16 Ps[8][16 * 64];   // per-wave P, swizzled

  const int tid = threadIdx.x;
  const int l = tid & 63, w = tid >> 6;          // 8 waves
  const int bh = blockIdx.x;                      // 0..63  (XCD = bh%8)
  // balanced qt permutation (see header comment)
  const int j = blockIdx.y;
  const int qt = (j < 4) ? j : (j < 8) ? 19 - j : (j < 12) ? 15 - j : j - 4;
  const size_t base = (size_t)bh * TT * DD;
  const int kp = tid & 31;
  const int dgr = tid >> 5;

  const int q0 = TT - 128 - qt * 128;             // qt=0 -> heaviest (nch=32)
  const int nch = (q0 >> 6) + 2;                  // always even
  const int wrow0 = q0 + w * 16;

  bf16x8 vones;
#pragma unroll
  for (int jj = 0; jj < 8; ++jj) vones[jj] = (short)0x3F80;

  auto stageK = [&](int k0, int buf) {
    int c = tid;
    int row = c >> 3, s = c & 7;
    int g = s ^ (row & 7);
    __builtin_amdgcn_global_load_lds(
        (const AS1 void*)(K + base + (size_t)(k0 + row) * DD + g * 8),
        (AS3 void*)(Ks[buf] + c * 8), 16, 0, 0);
  };
  auto loadV = [&](int k0, uint2& a0, uint2& a1) {
    const u16* vp0 = V + base + (size_t)(k0 + 2 * kp) * DD + dgr * 4;
    a0 = *(const uint2*)vp0;
    a1 = *(const uint2*)(vp0 + DD);
  };
  auto writeV = [&](int buf, uint2 a0, uint2 a1) {
    u16 v0[4], v1[4];
    *(uint2*)v0 = a0; *(uint2*)v1 = a1;
#pragma unroll
    for (int jj = 0; jj < 4; ++jj) {
      int d = dgr * 4 + jj;
      unsigned pk = (unsigned)v0[jj] | ((unsigned)v1[jj] << 16);
      int addr = d * 64 + (((kp >> 2) ^ (d & 7)) << 3) + ((kp & 3) << 1);
      *(unsigned*)(Vt[buf] + addr) = pk;
    }
  };

  // Q fragments (one 16-row tile per wave; Q pre-scaled by SL2E)
  const u16* qp = Q + base + (size_t)(wrow0 + (l & 15)) * DD + (l >> 4) * 8;
  bf16x8 qa0 = *(const bf16x8*)(qp);
  bf16x8 qa1 = *(const bf16x8*)(qp + 32);

  f32x4 oacc[5] = {};                             // [0..3]=O, [4]=rowsum

  auto body = [&](auto curC, auto maskedC, int k0) {
    constexpr int cur = decltype(curC)::value;
    constexpr bool masked = decltype(maskedC)::value;
    bool active = true;
    if (masked) active = (k0 <= wrow0 + 15);
    if (active) {
      const bool need_mask = masked && (k0 + 63 > wrow0);
      f32x4 sa[4];
#pragma unroll
      for (int nt = 0; nt < 4; ++nt) {
        int krow = nt * 16 + (l & 15);
        int rb = krow & 7;
        bf16x8 kb0 = *(const bf16x8*)(Ks[cur] + krow * 64 + (((l >> 4) ^ rb) << 3));
        bf16x8 kb1 = *(const bf16x8*)(Ks[cur] + krow * 64 + ((((l >> 4) + 4) ^ rb) << 3));
        f32x4 zz = {};
        zz = __builtin_amdgcn_mfma_f32_16x16x32_bf16(qa0, kb0, zz, 0, 0, 0);
        zz = __builtin_amdgcn_mfma_f32_16x16x32_bf16(qa1, kb1, zz, 0, 0, 0);
        sa[nt] = zz;
      }
#pragma unroll
      for (int r = 0; r < 4; ++r) {
        int lrow = ((l >> 4) << 2) + r;
        int row = wrow0 + lrow;
#pragma unroll
        for (int nt = 0; nt < 4; ++nt) {
          float p = exp2f(sa[nt][r]);
          if (masked) {
            if (need_mask) {
              int col = k0 + nt * 16 + (l & 15);
              if (col > row) p = 0.f;
            }
          }
          int slot = ((2 * nt + ((l & 15) >> 3)) & 7) ^ (lrow & 7);
          Ps[w][lrow * 64 + (slot << 3) + (l & 7)] =
              (u16)(__float_as_uint(p) >> 16);
        }
      }
      int arow = l & 15, ab = arow & 7;
      bf16x8 pa0 = *(const bf16x8*)(&Ps[w][arow * 64 + (((l >> 4) ^ ab) << 3)]);
      bf16x8 pa1 = *(const bf16x8*)(&Ps[w][arow * 64 + ((((l >> 4) + 4) ^ ab) << 3)]);
#pragma unroll
      for (int dt = 0; dt < 5; ++dt) {
        bf16x8 vb0, vb1;
        if (dt < 4) {
          int vrow = dt * 16 + (l & 15), vb = vrow & 7;
          vb0 = *(const bf16x8*)(Vt[cur] + vrow * 64 + (((l >> 4) ^ vb) << 3));
          vb1 = *(const bf16x8*)(Vt[cur] + vrow * 64 + ((((l >> 4) + 4) ^ vb) << 3));
        } else {
          vb0 = vones; vb1 = vones;
        }
        oacc[dt] = __builtin_amdgcn_mfma_f32_16x16x32_bf16(pa0, vb0, oacc[dt], 0, 0, 0);
        oacc[dt] = __builtin_amdgcn_mfma_f32_16x16x32_bf16(pa1, vb1, oacc[dt], 0, 0, 0);
      }
    }
  };

  constexpr std::integral_constant<int, 0> c0{};
  constexpr std::integral_constant<int, 1> c1{};
  constexpr std::false_type noMask{};
  constexpr std::true_type  doMask{};

  // prologue: stage chunk 0 into buffer 0
  {
    uint2 a0, a1;
    stageK(0, 0);
    loadV(0, a0, a1);
    writeV(0, a0, a1);
    __syncthreads();
  }

  const int mainN = nch - 2;                      // even
  for (int ch = 0; ch < mainN; ch += 2) {
    {
      uint2 na0, na1;
      stageK((ch + 1) * 64, 1);
      loadV((ch + 1) * 64, na0, na1);
      body(c0, noMask, ch * 64);
      writeV(1, na0, na1);
      __syncthreads();
    }
    {
      uint2 na0, na1;
      stageK((ch + 2) * 64, 0);
      loadV((ch + 2) * 64, na0, na1);
      body(c1, noMask, (ch + 1) * 64);
      writeV(0, na0, na1);
      __syncthreads();
    }
  }
  {
    uint2 na0, na1;
    stageK((nch - 1) * 64, 1);
    loadV((nch - 1) * 64, na0, na1);
    body(c0, doMask, (nch - 2) * 64);
    writeV(1, na0, na1);
    __syncthreads();
  }
  {
    body(c1, doMask, (nch - 1) * 64);
    __syncthreads();
  }

  // --- normalize + write O over Q (rows owned by this block only) ---
#pragma unroll
  for (int r = 0; r < 4; ++r) {
    float inv = 1.f / oacc[4][r];
    int t = wrow0 + ((l >> 4) << 2) + r;
#pragma unroll
    for (int dt = 0; dt < 4; ++dt)
      Q[base + (size_t)t * DD + dt * 16 + (l & 15)] = f2bf(oacc[dt][r] * inv);
  }
}

// ---------------- launcher ----------------
extern "C" void kernel_launch(void* const* d_in, const int* in_sizes, int n_in,
                              void* d_out, int out_size, void* d_ws, size_t ws_size,
                              hipStream_t stream) {
  const float* x  = (const float*)d_in[0];
  const float* wq = (const float*)d_in[1];
  const float* bq = (const float*)d_in[2];
  const float* wk = (const float*)d_in[3];
  const float* bk = (const float*)d_in[4];
  const float* wv = (const float*)d_in[5];
  const float* bv = (const float*)d_in[6];
  const float* wo = (const float*)d_in[7];
  const float* bo = (const float*)d_in[8];

  const size_t M   = 4 * (size_t)TT;           // 8192
  const size_t wtB = (size_t)CC * CC * 2;      // 2 MB per transposed weight
  const size_t qB  = M * CC * 2;               // 16.78 MB per Q/K/V tensor
  const size_t need = 4 * wtB + 3 * qB;        // 58,720,256 B

  if (ws_size < need) return;

  char* ws = (char*)d_ws;
  u16* wt_all = (u16*)ws;
  u16* Qb     = (u16*)(ws + 4 * wtB);
  u16* Kb     = Qb + M * CC;
  u16* Vb     = Kb + M * CC;
  // xb (bf16 x) lives in d_out's first half; gemm_out fully overwrites d_out.
  u16* xb     = (u16*)d_out;

  // 1) x -> bf16 into d_out scratch
  conv_f2bf<<<dim3(4096), dim3(256), 0, stream>>>(x, xb);

  // 2) transpose-convert the 4 weights
  transw<<<dim3(32, 32, 4), dim3(32, 8), 0, stream>>>(wq, wk, wv, wo, wt_all);

  // 3) QKV projections (BK=64, swizzled LDS) -> [B,H,T,D]; Q pre-scaled by SL2E
  gemm_qkv<<<dim3(CC / 128, M / 128, 3), dim3(256), 0, stream>>>(
      xb, wt_all, bq, bk, bv, Qb, Kb, Vb);

  // 4) causal attention v11 (balanced qt permutation)
  attn_kernel<<<dim3(4 * HH, 16), dim3(512), 0, stream>>>(Qb, Kb, Vb);

  // 5) output projection (BK=64, swizzled LDS) -> d_out (FP32)
  gemm_out<<<dim3(CC / 128, M / 128, 1), dim3(256), 0, stream>>>(
      Qb, wt_all + 3 * (size_t)CC * CC, bo, (float*)d_out);
}